// Round 6
// baseline (219.683 us; speedup 1.0000x reference)
//
#include <hip/hip_runtime.h>

// Problem constants (from reference setup_inputs)
constexpr int N = 50000;   // nodes
constexpr int E = 800000;  // edges
constexpr int F = 128;     // feature dim
constexpr int U = 256;     // output units

constexpr int R    = 8;        // counter replicas per row (contention /8)
constexpr int NK   = N * R;    // 400000 keys
constexpr int EBLK = E / 256;  // 3125 (exact)
constexpr int SBLK = (NK + 255) / 256;  // 1563
constexpr int CH   = (SBLK + 255) / 256;  // 7 per-thread chunk in scansum

typedef __attribute__((ext_vector_type(8))) short short8;
typedef __attribute__((ext_vector_type(4))) float float4v;

__device__ inline unsigned short f32_to_bf16(float x) {
    unsigned int u = __float_as_uint(x);
    unsigned int r = (u + 0x7fffu + ((u >> 16) & 1u)) >> 16;  // RNE
    return (unsigned short)r;
}

// ---------------------------------------------------------------------------
// 1) hist (+ fused W transpose): one u32 atomic per edge on a replicated
//    counter; returned old value = rank within (row, replica)
// ---------------------------------------------------------------------------
__global__ __launch_bounds__(256) void hist_kernel(const int* __restrict__ erow,
                                                   int* __restrict__ cnt,
                                                   int* __restrict__ rank,
                                                   const float* __restrict__ W,
                                                   unsigned short* __restrict__ Wt) {
    if (blockIdx.x >= EBLK) {  // tail blocks: W [128,256] f32 -> Wt [256,128] bf16
        int idx = (blockIdx.x - EBLK) * 256 + threadIdx.x;  // < 32768
        int k = idx >> 8;
        int n = idx & 255;
        Wt[n * F + k] = f32_to_bf16(W[idx]);
        return;
    }
    int e = blockIdx.x * 256 + threadIdx.x;
    int key = erow[e] * R + (blockIdx.x & (R - 1));
    rank[e] = atomicAdd(&cnt[key], 1);
}

// ---------------------------------------------------------------------------
// 2a) per-block sums of cnt (1563 blocks x 256)
// ---------------------------------------------------------------------------
__global__ __launch_bounds__(256) void blksum_kernel(const int* __restrict__ cnt,
                                                     int* __restrict__ blk_sum) {
    int i = blockIdx.x * 256 + threadIdx.x;
    int v = (i < NK) ? cnt[i] : 0;
    #pragma unroll
    for (int off = 32; off > 0; off >>= 1) v += __shfl_down(v, off, 64);
    __shared__ int s[4];
    if ((threadIdx.x & 63) == 0) s[threadIdx.x >> 6] = v;
    __syncthreads();
    if (threadIdx.x == 0) blk_sum[blockIdx.x] = s[0] + s[1] + s[2] + s[3];
}

// ---------------------------------------------------------------------------
// 2b) exclusive scan of the 1563 block sums (1 block x 256, 7/thread)
// ---------------------------------------------------------------------------
__global__ __launch_bounds__(256) void scansum_kernel(const int* __restrict__ blk_sum,
                                                      int* __restrict__ blk_off,
                                                      int* __restrict__ rp2) {
    __shared__ int sh[256];
    int t = threadIdx.x;
    int loc[CH];
    int s = 0;
    #pragma unroll
    for (int i = 0; i < CH; ++i) {
        int idx = t * CH + i;
        int v = (idx < SBLK) ? blk_sum[idx] : 0;
        loc[i] = v;
        s += v;
    }
    sh[t] = s;
    __syncthreads();
    for (int off = 1; off < 256; off <<= 1) {
        int u = (t >= off) ? sh[t - off] : 0;
        __syncthreads();
        sh[t] += u;
        __syncthreads();
    }
    int run = sh[t] - s;  // exclusive prefix
    #pragma unroll
    for (int i = 0; i < CH; ++i) {
        int idx = t * CH + i;
        if (idx < SBLK) {
            blk_off[idx] = run;
            run += loc[i];
        }
    }
    if (t == 0) rp2[NK] = E;
}

// ---------------------------------------------------------------------------
// 2c) per-block scan + global offset -> rp2 (1563 blocks x 256)
// ---------------------------------------------------------------------------
__global__ __launch_bounds__(256) void blkscan_kernel(const int* __restrict__ cnt,
                                                      const int* __restrict__ blk_off,
                                                      int* __restrict__ rp2) {
    __shared__ int sh[256];
    int t = threadIdx.x;
    int i = blockIdx.x * 256 + t;
    int v = (i < NK) ? cnt[i] : 0;
    sh[t] = v;
    __syncthreads();
    for (int off = 1; off < 256; off <<= 1) {
        int u = (t >= off) ? sh[t - off] : 0;
        __syncthreads();
        sh[t] += u;
        __syncthreads();
    }
    if (i < NK) rp2[i] = blk_off[blockIdx.x] + sh[t] - v;
}

// ---------------------------------------------------------------------------
// 3) permute edges into CSR order — NO atomics
// ---------------------------------------------------------------------------
__global__ __launch_bounds__(256) void permute_kernel(const int* __restrict__ erow,
                                                      const int* __restrict__ ecol,
                                                      const float* __restrict__ eval,
                                                      const int* __restrict__ rank,
                                                      const int* __restrict__ rp2,
                                                      int2* __restrict__ csr) {
    int e = blockIdx.x * 256 + threadIdx.x;
    if (e < E) {
        int key = erow[e] * R + (blockIdx.x & (R - 1));
        int p = rp2[key] + rank[e];
        csr[p] = make_int2(ecol[e], __float_as_int(eval[e]));
    }
}

// ---------------------------------------------------------------------------
// 4) norm: wave per node. deg = exact fp32 segmented sum of csr row vals;
//    iv = rsqrt(deg+1) stored for gather; nrm = iv*feat as bf16.
// ---------------------------------------------------------------------------
__global__ __launch_bounds__(256) void norm_kernel(const float* __restrict__ feat,
                                                   const int* __restrict__ rp2,
                                                   const int2* __restrict__ csr,
                                                   float* __restrict__ iv,
                                                   unsigned int* __restrict__ nrm) {
    int gtid = blockIdx.x * 256 + threadIdx.x;
    int n    = gtid >> 6;
    int lane = threadIdx.x & 63;
    if (n >= N) return;

    int e0 = rp2[n * R], e1 = rp2[n * R + R];
    float s = 0.f;
    for (int e = e0 + lane; e < e1; e += 64) s += __int_as_float(csr[e].y);
    #pragma unroll
    for (int off = 32; off > 0; off >>= 1) s += __shfl_xor(s, off, 64);
    float iv_ = rsqrtf(s + 1.0f);
    if (lane == 0) iv[n] = iv_;

    float2 f = ((const float2*)feat)[n * 64 + lane];
    nrm[n * 64 + lane] =
        (unsigned int)f32_to_bf16(iv_ * f.x) | ((unsigned int)f32_to_bf16(iv_ * f.y) << 16);
}

// ---------------------------------------------------------------------------
// 5) gather: pooled[n] = iv^2*feat[n] + sum_e val*nrm[col]  -> bf16 output
//    one wave per node; 4-edge unrolled load batch for MLP
// ---------------------------------------------------------------------------
__global__ __launch_bounds__(256) void gather_kernel(const int* __restrict__ rp2,
                                                     const int2* __restrict__ csr,
                                                     const unsigned short* __restrict__ nrm,
                                                     const float* __restrict__ iv,
                                                     const float* __restrict__ feat,
                                                     unsigned int* __restrict__ pooledb) {
    int gtid = blockIdx.x * 256 + threadIdx.x;
    int n    = gtid >> 6;
    int lane = threadIdx.x & 63;
    if (n >= N) return;

    float iv_ = iv[n];
    float iv2 = iv_ * iv_;
    float2 f = ((const float2*)feat)[n * 64 + lane];
    float acc0 = iv2 * f.x;
    float acc1 = iv2 * f.y;

    int e = rp2[n * R], e1 = rp2[n * R + R];
    for (; e + 3 < e1; e += 4) {
        int2 p0 = csr[e], p1 = csr[e + 1], p2 = csr[e + 2], p3 = csr[e + 3];
        unsigned int u0 = *(const unsigned int*)&nrm[(size_t)p0.x * F + lane * 2];
        unsigned int u1 = *(const unsigned int*)&nrm[(size_t)p1.x * F + lane * 2];
        unsigned int u2 = *(const unsigned int*)&nrm[(size_t)p2.x * F + lane * 2];
        unsigned int u3 = *(const unsigned int*)&nrm[(size_t)p3.x * F + lane * 2];
        float v0 = __int_as_float(p0.y), v1 = __int_as_float(p1.y);
        float v2 = __int_as_float(p2.y), v3 = __int_as_float(p3.y);
        acc0 += v0 * __uint_as_float(u0 << 16);
        acc1 += v0 * __uint_as_float(u0 & 0xffff0000u);
        acc0 += v1 * __uint_as_float(u1 << 16);
        acc1 += v1 * __uint_as_float(u1 & 0xffff0000u);
        acc0 += v2 * __uint_as_float(u2 << 16);
        acc1 += v2 * __uint_as_float(u2 & 0xffff0000u);
        acc0 += v3 * __uint_as_float(u3 << 16);
        acc1 += v3 * __uint_as_float(u3 & 0xffff0000u);
    }
    for (; e < e1; ++e) {
        int2 p0 = csr[e];
        unsigned int u0 = *(const unsigned int*)&nrm[(size_t)p0.x * F + lane * 2];
        float v0 = __int_as_float(p0.y);
        acc0 += v0 * __uint_as_float(u0 << 16);
        acc1 += v0 * __uint_as_float(u0 & 0xffff0000u);
    }
    pooledb[n * 64 + lane] =
        (unsigned int)f32_to_bf16(acc0) | ((unsigned int)f32_to_bf16(acc1) << 16);
}

// ---------------------------------------------------------------------------
// 6) out = relu(pooled_bf16 @ W)  via MFMA 16x16x32 bf16. (unchanged)
// ---------------------------------------------------------------------------
__global__ __launch_bounds__(256) void gemm_mfma_kernel(const unsigned short* __restrict__ Ab,
                                                        const unsigned short* __restrict__ Wt,
                                                        float* __restrict__ out) {
    __shared__ unsigned short As[16384];  // 32 KB, [ks(4)][mt(8)][lane(64)][8]
    __shared__ unsigned short Bs[16384];  // 32 KB, [ks(4)][nt(8)][lane(64)][8]
    const int tid = threadIdx.x;
    const int m0 = blockIdx.x * 128;
    const int n0 = blockIdx.y * 128;

    {
        const int r = tid >> 1;
        const int h = tid & 1;
        const int grow = m0 + r;
        const uint4* asrc = (grow < N) ? (const uint4*)(Ab + (size_t)grow * F) : nullptr;
        const uint4* bsrc = (const uint4*)(Wt + (size_t)(n0 + r) * F);
        #pragma unroll
        for (int j = 0; j < 8; ++j) {
            int o = h * 8 + j;
            int ks = o >> 2, quad = o & 3;
            int slot = ((ks * 8 + (r >> 4)) * 64) + (quad << 4) + (r & 15);
            uint4 av = asrc ? asrc[o] : make_uint4(0u, 0u, 0u, 0u);
            ((uint4*)As)[slot] = av;
            ((uint4*)Bs)[slot] = bsrc[o];
        }
    }
    __syncthreads();

    const int wave = tid >> 6;
    const int lane = tid & 63;
    float4v acc[8][2];
    #pragma unroll
    for (int i = 0; i < 8; ++i) {
        acc[i][0] = (float4v){0.f, 0.f, 0.f, 0.f};
        acc[i][1] = (float4v){0.f, 0.f, 0.f, 0.f};
    }

    #pragma unroll
    for (int ks = 0; ks < 4; ++ks) {
        short8 b0 = *(const short8*)&Bs[(((ks * 8 + wave * 2 + 0) * 64) + lane) * 8];
        short8 b1 = *(const short8*)&Bs[(((ks * 8 + wave * 2 + 1) * 64) + lane) * 8];
        #pragma unroll
        for (int mt = 0; mt < 8; ++mt) {
            short8 a = *(const short8*)&As[(((ks * 8 + mt) * 64) + lane) * 8];
            acc[mt][0] = __builtin_amdgcn_mfma_f32_16x16x32_bf16(a, b0, acc[mt][0], 0, 0, 0);
            acc[mt][1] = __builtin_amdgcn_mfma_f32_16x16x32_bf16(a, b1, acc[mt][1], 0, 0, 0);
        }
    }

    const int quad = lane >> 4;
    const int colt = lane & 15;
    #pragma unroll
    for (int mt = 0; mt < 8; ++mt) {
        #pragma unroll
        for (int nt = 0; nt < 2; ++nt) {
            int col = n0 + (wave * 2 + nt) * 16 + colt;
            #pragma unroll
            for (int i = 0; i < 4; ++i) {
                int row = m0 + mt * 16 + quad * 4 + i;
                if (row < N) out[(size_t)row * U + col] = fmaxf(acc[mt][nt][i], 0.f);
            }
        }
    }
}

// ---------------------------------------------------------------------------
extern "C" void kernel_launch(void* const* d_in, const int* in_sizes, int n_in,
                              void* d_out, int out_size, void* d_ws, size_t ws_size,
                              hipStream_t stream) {
    (void)in_sizes; (void)n_in; (void)out_size; (void)ws_size;

    const float* feat = (const float*)d_in[0];  // [N,128]
    const int*   erow = (const int*)d_in[1];    // [E]
    const int*   ecol = (const int*)d_in[2];    // [E]
    const float* eval = (const float*)d_in[3];  // [E]
    const float* W    = (const float*)d_in[4];  // [128,256]
    float* out = (float*)d_out;                 // [N,256]

    // workspace layout (byte offsets)
    char* ws = (char*)d_ws;
    int*            cnt     = (int*)  (ws + 0);           // NK      (1.6 MB)
    int*            rp2     = (int*)  (ws + 1600000);     // NK+1    (1.6 MB)
    int*            blk_sum = (int*)  (ws + 3200064);     // 1563
    int*            blk_off = (int*)  (ws + 3206336);     // 1563
    int*            rank    = (int*)  (ws + 3212608);     // E       (3.2 MB)
    int2*           csr     = (int2*) (ws + 6412608);     // E int2  (6.4 MB)
    float*          iv      = (float*)(ws + 12812608);    // N       (200 KB)
    unsigned short* Wt      = (unsigned short*)(ws + 13012608);  // 256*128 bf16 (64 KB)
    unsigned short* nrm     = (unsigned short*)(ws + 13078144);  // N*F bf16 (12.8 MB)
    unsigned int*   pooledb = (unsigned int*)  (ws + 25878144);  // N*F bf16 (12.8 MB)
    // total ~38.7 MB

    (void)hipMemsetAsync(cnt, 0, (size_t)NK * sizeof(int), stream);

    hist_kernel<<<EBLK + (F * U) / 256, 256, 0, stream>>>(erow, cnt, rank, W, Wt);

    blksum_kernel <<<SBLK, 256, 0, stream>>>(cnt, blk_sum);
    scansum_kernel<<<1,    256, 0, stream>>>(blk_sum, blk_off, rp2);
    blkscan_kernel<<<SBLK, 256, 0, stream>>>(cnt, blk_off, rp2);

    permute_kernel<<<EBLK, 256, 0, stream>>>(erow, ecol, eval, rank, rp2, csr);
    norm_kernel  <<<(N * 64) / 256, 256, 0, stream>>>(feat, rp2, csr, iv, (unsigned int*)nrm);
    gather_kernel<<<(N * 64) / 256, 256, 0, stream>>>(rp2, csr, nrm, iv, feat, pooledb);

    dim3 ggrid((N + 127) / 128, U / 128);
    gemm_mfma_kernel<<<ggrid, 256, 0, stream>>>((const unsigned short*)pooledb, Wt, out);
}

// Round 7
// 213.592 us; speedup vs baseline: 1.0285x; 1.0285x over previous
//
#include <hip/hip_runtime.h>

// Problem constants (from reference setup_inputs)
constexpr int N = 50000;   // nodes
constexpr int E = 800000;  // edges
constexpr int F = 128;     // feature dim
constexpr int U = 256;     // output units

constexpr int R    = 8;        // counter replicas per row (contention /8)
constexpr int NK   = N * R;    // 400000 keys
constexpr int EBLK = E / 256;  // 3125 (exact)
constexpr int SBLK = (NK + 255) / 256;  // 1563
constexpr int CH   = (SBLK + 255) / 256;  // 7 per-thread chunk in scansum

typedef __attribute__((ext_vector_type(8))) short short8;
typedef __attribute__((ext_vector_type(4))) float float4v;

__device__ inline unsigned short f32_to_bf16(float x) {
    unsigned int u = __float_as_uint(x);
    unsigned int r = (u + 0x7fffu + ((u >> 16) & 1u)) >> 16;  // RNE
    return (unsigned short)r;
}
__device__ inline float bf_lo(unsigned int u) { return __uint_as_float(u << 16); }
__device__ inline float bf_hi(unsigned int u) { return __uint_as_float(u & 0xffff0000u); }

// ---------------------------------------------------------------------------
// 1) hist (+ fused W transpose): one u32 atomic per edge on a replicated
//    counter; stores (key<<12)|rank so permute needs no erow re-read
// ---------------------------------------------------------------------------
__global__ __launch_bounds__(256) void hist_kernel(const int* __restrict__ erow,
                                                   int* __restrict__ cnt,
                                                   unsigned int* __restrict__ rankp,
                                                   const float* __restrict__ W,
                                                   unsigned short* __restrict__ Wt) {
    if (blockIdx.x >= EBLK) {  // tail blocks: W [128,256] f32 -> Wt [256,128] bf16
        int idx = (blockIdx.x - EBLK) * 256 + threadIdx.x;  // < 32768
        int k = idx >> 8;
        int n = idx & 255;
        Wt[n * F + k] = f32_to_bf16(W[idx]);
        return;
    }
    int e = blockIdx.x * 256 + threadIdx.x;
    int key = erow[e] * R + (blockIdx.x & (R - 1));   // key < 400000 < 2^19
    int rk = atomicAdd(&cnt[key], 1);                  // bucket rank (< 4096 easily)
    rankp[e] = ((unsigned int)key << 12) | (unsigned int)rk;
}

// ---------------------------------------------------------------------------
// 2a) per-block sums of cnt (1563 blocks x 256)
// ---------------------------------------------------------------------------
__global__ __launch_bounds__(256) void blksum_kernel(const int* __restrict__ cnt,
                                                     int* __restrict__ blk_sum) {
    int i = blockIdx.x * 256 + threadIdx.x;
    int v = (i < NK) ? cnt[i] : 0;
    #pragma unroll
    for (int off = 32; off > 0; off >>= 1) v += __shfl_down(v, off, 64);
    __shared__ int s[4];
    if ((threadIdx.x & 63) == 0) s[threadIdx.x >> 6] = v;
    __syncthreads();
    if (threadIdx.x == 0) blk_sum[blockIdx.x] = s[0] + s[1] + s[2] + s[3];
}

// ---------------------------------------------------------------------------
// 2b) exclusive scan of the 1563 block sums (1 block x 256, 7/thread)
// ---------------------------------------------------------------------------
__global__ __launch_bounds__(256) void scansum_kernel(const int* __restrict__ blk_sum,
                                                      int* __restrict__ blk_off,
                                                      int* __restrict__ rp2) {
    __shared__ int sh[256];
    int t = threadIdx.x;
    int loc[CH];
    int s = 0;
    #pragma unroll
    for (int i = 0; i < CH; ++i) {
        int idx = t * CH + i;
        int v = (idx < SBLK) ? blk_sum[idx] : 0;
        loc[i] = v;
        s += v;
    }
    sh[t] = s;
    __syncthreads();
    for (int off = 1; off < 256; off <<= 1) {
        int u = (t >= off) ? sh[t - off] : 0;
        __syncthreads();
        sh[t] += u;
        __syncthreads();
    }
    int run = sh[t] - s;  // exclusive prefix
    #pragma unroll
    for (int i = 0; i < CH; ++i) {
        int idx = t * CH + i;
        if (idx < SBLK) {
            blk_off[idx] = run;
            run += loc[i];
        }
    }
    if (t == 0) rp2[NK] = E;
}

// ---------------------------------------------------------------------------
// 2c) per-block scan + global offset -> rp2 (1563 blocks x 256)
// ---------------------------------------------------------------------------
__global__ __launch_bounds__(256) void blkscan_kernel(const int* __restrict__ cnt,
                                                      const int* __restrict__ blk_off,
                                                      int* __restrict__ rp2) {
    __shared__ int sh[256];
    int t = threadIdx.x;
    int i = blockIdx.x * 256 + t;
    int v = (i < NK) ? cnt[i] : 0;
    sh[t] = v;
    __syncthreads();
    for (int off = 1; off < 256; off <<= 1) {
        int u = (t >= off) ? sh[t - off] : 0;
        __syncthreads();
        sh[t] += u;
        __syncthreads();
    }
    if (i < NK) rp2[i] = blk_off[blockIdx.x] + sh[t] - v;
}

// ---------------------------------------------------------------------------
// 3) permute edges into CSR order — no atomics, no erow re-read
// ---------------------------------------------------------------------------
__global__ __launch_bounds__(256) void permute_kernel(const int* __restrict__ ecol,
                                                      const float* __restrict__ eval,
                                                      const unsigned int* __restrict__ rankp,
                                                      const int* __restrict__ rp2,
                                                      int2* __restrict__ csr) {
    int e = blockIdx.x * 256 + threadIdx.x;
    if (e < E) {
        unsigned int pk = rankp[e];
        int p = rp2[pk >> 12] + (int)(pk & 0xFFFu);
        csr[p] = make_int2(ecol[e], __float_as_int(eval[e]));
    }
}

// ---------------------------------------------------------------------------
// 4) norm: wave per node. deg = exact fp32 segmented sum of csr row vals;
//    iv = rsqrt(deg+1) stored for gather; nrm = iv*feat as bf16.
// ---------------------------------------------------------------------------
__global__ __launch_bounds__(256) void norm_kernel(const float* __restrict__ feat,
                                                   const int* __restrict__ rp2,
                                                   const int2* __restrict__ csr,
                                                   float* __restrict__ iv,
                                                   unsigned int* __restrict__ nrm) {
    int gtid = blockIdx.x * 256 + threadIdx.x;
    int n    = gtid >> 6;
    int lane = threadIdx.x & 63;
    if (n >= N) return;

    int e0 = rp2[n * R], e1 = rp2[n * R + R];
    float s = 0.f;
    for (int e = e0 + lane; e < e1; e += 64) s += __int_as_float(csr[e].y);
    #pragma unroll
    for (int off = 32; off > 0; off >>= 1) s += __shfl_xor(s, off, 64);
    float iv_ = rsqrtf(s + 1.0f);
    if (lane == 0) iv[n] = iv_;

    float2 f = ((const float2*)feat)[n * 64 + lane];
    nrm[n * 64 + lane] =
        (unsigned int)f32_to_bf16(iv_ * f.x) | ((unsigned int)f32_to_bf16(iv_ * f.y) << 16);
}

// ---------------------------------------------------------------------------
// 5) gather: pooled[n] = iv*nrm[n] + sum_e val*nrm[col]  -> bf16 output
//    wave per node; self term from own nrm row (no feat re-read);
//    8-wide edge unroll for deep MLP on the csr->nrm dependent chain
// ---------------------------------------------------------------------------
__global__ __launch_bounds__(256) void gather_kernel(const int* __restrict__ rp2,
                                                     const int2* __restrict__ csr,
                                                     const unsigned int* __restrict__ nrm,
                                                     const float* __restrict__ iv,
                                                     unsigned int* __restrict__ pooledb) {
    int gtid = blockIdx.x * 256 + threadIdx.x;
    int n    = gtid >> 6;
    int lane = threadIdx.x & 63;
    if (n >= N) return;

    float iv_ = iv[n];
    unsigned int self = nrm[n * 64 + lane];
    float acc0 = iv_ * bf_lo(self);
    float acc1 = iv_ * bf_hi(self);

    int e = rp2[n * R], e1 = rp2[n * R + R];
    for (; e + 7 < e1; e += 8) {
        int2 p0 = csr[e],     p1 = csr[e + 1], p2 = csr[e + 2], p3 = csr[e + 3];
        int2 p4 = csr[e + 4], p5 = csr[e + 5], p6 = csr[e + 6], p7 = csr[e + 7];
        unsigned int u0 = nrm[(size_t)p0.x * 64 + lane];
        unsigned int u1 = nrm[(size_t)p1.x * 64 + lane];
        unsigned int u2 = nrm[(size_t)p2.x * 64 + lane];
        unsigned int u3 = nrm[(size_t)p3.x * 64 + lane];
        unsigned int u4 = nrm[(size_t)p4.x * 64 + lane];
        unsigned int u5 = nrm[(size_t)p5.x * 64 + lane];
        unsigned int u6 = nrm[(size_t)p6.x * 64 + lane];
        unsigned int u7 = nrm[(size_t)p7.x * 64 + lane];
        acc0 += __int_as_float(p0.y) * bf_lo(u0); acc1 += __int_as_float(p0.y) * bf_hi(u0);
        acc0 += __int_as_float(p1.y) * bf_lo(u1); acc1 += __int_as_float(p1.y) * bf_hi(u1);
        acc0 += __int_as_float(p2.y) * bf_lo(u2); acc1 += __int_as_float(p2.y) * bf_hi(u2);
        acc0 += __int_as_float(p3.y) * bf_lo(u3); acc1 += __int_as_float(p3.y) * bf_hi(u3);
        acc0 += __int_as_float(p4.y) * bf_lo(u4); acc1 += __int_as_float(p4.y) * bf_hi(u4);
        acc0 += __int_as_float(p5.y) * bf_lo(u5); acc1 += __int_as_float(p5.y) * bf_hi(u5);
        acc0 += __int_as_float(p6.y) * bf_lo(u6); acc1 += __int_as_float(p6.y) * bf_hi(u6);
        acc0 += __int_as_float(p7.y) * bf_lo(u7); acc1 += __int_as_float(p7.y) * bf_hi(u7);
    }
    for (; e + 3 < e1; e += 4) {
        int2 p0 = csr[e], p1 = csr[e + 1], p2 = csr[e + 2], p3 = csr[e + 3];
        unsigned int u0 = nrm[(size_t)p0.x * 64 + lane];
        unsigned int u1 = nrm[(size_t)p1.x * 64 + lane];
        unsigned int u2 = nrm[(size_t)p2.x * 64 + lane];
        unsigned int u3 = nrm[(size_t)p3.x * 64 + lane];
        acc0 += __int_as_float(p0.y) * bf_lo(u0); acc1 += __int_as_float(p0.y) * bf_hi(u0);
        acc0 += __int_as_float(p1.y) * bf_lo(u1); acc1 += __int_as_float(p1.y) * bf_hi(u1);
        acc0 += __int_as_float(p2.y) * bf_lo(u2); acc1 += __int_as_float(p2.y) * bf_hi(u2);
        acc0 += __int_as_float(p3.y) * bf_lo(u3); acc1 += __int_as_float(p3.y) * bf_hi(u3);
    }
    for (; e < e1; ++e) {
        int2 p0 = csr[e];
        unsigned int u0 = nrm[(size_t)p0.x * 64 + lane];
        acc0 += __int_as_float(p0.y) * bf_lo(u0);
        acc1 += __int_as_float(p0.y) * bf_hi(u0);
    }
    pooledb[n * 64 + lane] =
        (unsigned int)f32_to_bf16(acc0) | ((unsigned int)f32_to_bf16(acc1) << 16);
}

// ---------------------------------------------------------------------------
// 6) out = relu(pooled_bf16 @ W)  via MFMA 16x16x32 bf16. (unchanged)
// ---------------------------------------------------------------------------
__global__ __launch_bounds__(256) void gemm_mfma_kernel(const unsigned short* __restrict__ Ab,
                                                        const unsigned short* __restrict__ Wt,
                                                        float* __restrict__ out) {
    __shared__ unsigned short As[16384];  // 32 KB, [ks(4)][mt(8)][lane(64)][8]
    __shared__ unsigned short Bs[16384];  // 32 KB, [ks(4)][nt(8)][lane(64)][8]
    const int tid = threadIdx.x;
    const int m0 = blockIdx.x * 128;
    const int n0 = blockIdx.y * 128;

    {
        const int r = tid >> 1;
        const int h = tid & 1;
        const int grow = m0 + r;
        const uint4* asrc = (grow < N) ? (const uint4*)(Ab + (size_t)grow * F) : nullptr;
        const uint4* bsrc = (const uint4*)(Wt + (size_t)(n0 + r) * F);
        #pragma unroll
        for (int j = 0; j < 8; ++j) {
            int o = h * 8 + j;
            int ks = o >> 2, quad = o & 3;
            int slot = ((ks * 8 + (r >> 4)) * 64) + (quad << 4) + (r & 15);
            uint4 av = asrc ? asrc[o] : make_uint4(0u, 0u, 0u, 0u);
            ((uint4*)As)[slot] = av;
            ((uint4*)Bs)[slot] = bsrc[o];
        }
    }
    __syncthreads();

    const int wave = tid >> 6;
    const int lane = tid & 63;
    float4v acc[8][2];
    #pragma unroll
    for (int i = 0; i < 8; ++i) {
        acc[i][0] = (float4v){0.f, 0.f, 0.f, 0.f};
        acc[i][1] = (float4v){0.f, 0.f, 0.f, 0.f};
    }

    #pragma unroll
    for (int ks = 0; ks < 4; ++ks) {
        short8 b0 = *(const short8*)&Bs[(((ks * 8 + wave * 2 + 0) * 64) + lane) * 8];
        short8 b1 = *(const short8*)&Bs[(((ks * 8 + wave * 2 + 1) * 64) + lane) * 8];
        #pragma unroll
        for (int mt = 0; mt < 8; ++mt) {
            short8 a = *(const short8*)&As[(((ks * 8 + mt) * 64) + lane) * 8];
            acc[mt][0] = __builtin_amdgcn_mfma_f32_16x16x32_bf16(a, b0, acc[mt][0], 0, 0, 0);
            acc[mt][1] = __builtin_amdgcn_mfma_f32_16x16x32_bf16(a, b1, acc[mt][1], 0, 0, 0);
        }
    }

    const int quad = lane >> 4;
    const int colt = lane & 15;
    #pragma unroll
    for (int mt = 0; mt < 8; ++mt) {
        #pragma unroll
        for (int nt = 0; nt < 2; ++nt) {
            int col = n0 + (wave * 2 + nt) * 16 + colt;
            #pragma unroll
            for (int i = 0; i < 4; ++i) {
                int row = m0 + mt * 16 + quad * 4 + i;
                if (row < N) out[(size_t)row * U + col] = fmaxf(acc[mt][nt][i], 0.f);
            }
        }
    }
}

// ---------------------------------------------------------------------------
extern "C" void kernel_launch(void* const* d_in, const int* in_sizes, int n_in,
                              void* d_out, int out_size, void* d_ws, size_t ws_size,
                              hipStream_t stream) {
    (void)in_sizes; (void)n_in; (void)out_size; (void)ws_size;

    const float* feat = (const float*)d_in[0];  // [N,128]
    const int*   erow = (const int*)d_in[1];    // [E]
    const int*   ecol = (const int*)d_in[2];    // [E]
    const float* eval = (const float*)d_in[3];  // [E]
    const float* W    = (const float*)d_in[4];  // [128,256]
    float* out = (float*)d_out;                 // [N,256]

    // workspace layout (byte offsets)
    char* ws = (char*)d_ws;
    int*            cnt     = (int*)  (ws + 0);           // NK      (1.6 MB)
    int*            rp2     = (int*)  (ws + 1600000);     // NK+1    (1.6 MB)
    int*            blk_sum = (int*)  (ws + 3200064);     // 1563
    int*            blk_off = (int*)  (ws + 3206336);     // 1563
    unsigned int*   rankp   = (unsigned int*)(ws + 3212608);  // E  (3.2 MB)
    int2*           csr     = (int2*) (ws + 6412608);     // E int2  (6.4 MB)
    float*          iv      = (float*)(ws + 12812608);    // N       (200 KB)
    unsigned short* Wt      = (unsigned short*)(ws + 13012608);  // 256*128 bf16 (64 KB)
    unsigned int*   nrm     = (unsigned int*)  (ws + 13078144);  // N*F bf16 (12.8 MB)
    unsigned int*   pooledb = (unsigned int*)  (ws + 25878144);  // N*F bf16 (12.8 MB)
    // total ~38.7 MB

    (void)hipMemsetAsync(cnt, 0, (size_t)NK * sizeof(int), stream);

    hist_kernel<<<EBLK + (F * U) / 256, 256, 0, stream>>>(erow, cnt, rankp, W, Wt);

    blksum_kernel <<<SBLK, 256, 0, stream>>>(cnt, blk_sum);
    scansum_kernel<<<1,    256, 0, stream>>>(blk_sum, blk_off, rp2);
    blkscan_kernel<<<SBLK, 256, 0, stream>>>(cnt, blk_off, rp2);

    permute_kernel<<<EBLK, 256, 0, stream>>>(ecol, eval, rankp, rp2, csr);
    norm_kernel  <<<(N * 64) / 256, 256, 0, stream>>>(feat, rp2, csr, iv, nrm);
    gather_kernel<<<(N * 64) / 256, 256, 0, stream>>>(rp2, csr, nrm, iv, pooledb);

    dim3 ggrid((N + 127) / 128, U / 128);
    gemm_mfma_kernel<<<ggrid, 256, 0, stream>>>((const unsigned short*)pooledb, Wt, out);
}